// Round 6
// baseline (1201.081 us; speedup 1.0000x reference)
//
#include <hip/hip_runtime.h>

typedef short v8s __attribute__((ext_vector_type(8)));   // 8 x bf16 (4 VGPR)
typedef float v4f __attribute__((ext_vector_type(4)));

// HW packed f32->bf16 (RNE), 2 elems/instr. No builtin on gfx950 -> inline asm.
__device__ __forceinline__ unsigned cvtpk(float lo, float hi) {
    unsigned r;
    asm("v_cvt_pk_bf16_f32 %0, %1, %2" : "=v"(r) : "v"(lo), "v"(hi));
    return r;
}
__device__ __forceinline__ v8s pack8(float4 f0, float4 f1) {
    union { unsigned u[4]; v8s v; } r;
    r.u[0] = cvtpk(f0.x, f0.y); r.u[1] = cvtpk(f0.z, f0.w);
    r.u[2] = cvtpk(f1.x, f1.y); r.u[3] = cvtpk(f1.z, f1.w);
    return r.v;
}
__device__ __forceinline__ v4f mfma(v8s a, v8s b, v4f c) {
    return __builtin_amdgcn_mfma_f32_16x16x32_bf16(a, b, c, 0, 0, 0);
}
// B-frag for Z = Xin @ W^T from f32 W: lane holds W[n][k0..k0+7] as bf16.
__device__ __forceinline__ v8s ldwf(const float* W, int rowElems, int n, int k0) {
    const float* p = W + (size_t)n * rowElems + k0;
    union { unsigned u[4]; v8s v; } r;
    #pragma unroll
    for (int j = 0; j < 4; ++j) r.u[j] = cvtpk(p[2 * j], p[2 * j + 1]);
    return r.v;
}

// Fused-denominator LSTM cell: 5 exp2 + 2 rcp. (verified R3/R4, absmax 0.015625)
__device__ __forceinline__ float cell(float zi, float zf, float zg, float zo, float& c) {
    const float NL = -1.44269504f, PG = 2.88539008f;
    float ei = __builtin_amdgcn_exp2f(NL * zi);
    float ef = __builtin_amdgcn_exp2f(NL * zf);
    float eg = __builtin_amdgcn_exp2f(PG * zg);
    float Df = 1.f + ef;
    float Dig = (1.f + ei) * (1.f + eg);
    float cc = (c * Dig + Df * (eg - 1.f)) * __builtin_amdgcn_rcpf(Df * Dig);
    c = cc;
    float eo = __builtin_amdgcn_exp2f(NL * zo);
    float ec = __builtin_amdgcn_exp2f(fminf(PG * cc, 60.f));
    return (ec - 1.f) * __builtin_amdgcn_rcpf((1.f + eo) * (1.f + ec));
}

// Register model (R1/R4/R5 evidence): reported VGPR_Count = arch VGPRs only;
// waves/SIMD = 512 / (VGPR+AGPR total). (256,2) -> ~192 total -> 2 waves/SIMD
// (20.9% occ). (256,4) -> 128 budget -> spills (R1/R5). Live set here is ~168
// regs -> (256,3)'s 170-budget fits WITHOUT spills -> 3 waves/SIMD target.
__global__ __launch_bounds__(256, 3) void seq2seq(
    const float* __restrict__ X,
    const float* __restrict__ bias,
    const float* __restrict__ eWih0, const float* __restrict__ eWhh0, const float* __restrict__ eb0,
    const float* __restrict__ eWih1, const float* __restrict__ eWhh1, const float* __restrict__ eb1,
    const float* __restrict__ dWih0, const float* __restrict__ dWhh0, const float* __restrict__ db0,
    const float* __restrict__ dWih1, const float* __restrict__ dWhh1, const float* __restrict__ db1,
    const float* __restrict__ rW1, const float* __restrict__ rb1,
    const float* __restrict__ rW2, const float* __restrict__ rb2,
    float* __restrict__ out)
{
    // h staging, frag-linear: [parity][kk*512 + lane*8 + j], bf16 single-plane.
    // 16 rows/block: 2 KB per buffer.
    __shared__ __align__(16) short sh0[2][1024];
    __shared__ __align__(16) short sh1[2][1024];
    __shared__ __align__(16) short sy1[1024];

    const int tid  = threadIdx.x;
    const int lane = tid & 63;
    const int w    = tid >> 6;            // unit-group 0..3 (units 16w..16w+15)
    const int lo   = lane & 15, hi = lane >> 4;
    const int wg   = blockIdx.x;          // 16 batch rows per block

    // zero parity-1 staging (initial h = 0): shorts [1024,2048) = ints [512,1024)
    for (int i = tid; i < 512; i += 256) {
        ((int*)sh0)[512 + i] = 0;
        ((int*)sh1)[512 + i] = 0;
    }

    // staging write index for value (m = hi*4+q, u = 16w+lo):
    const int wsidx = (w >> 1) * 512 + (((2 * w) + (lo >> 3)) & 3) * 128 + hi * 32 + (lo & 7);

    // ---- encoder weights -> register B-frags (f32 -> bf16) ----
    v8s wf[4][4][2];                      // [matrix][gate g (Ntile=w+4g)][kstep]
    float bz0[4], bz1[4];
    #pragma unroll
    for (int g = 0; g < 4; ++g) {
        const int n = (w + 4 * g) * 16 + lo;       // z column (row of W)
        v8s z = {0, 0, 0, 0, 0, 0, 0, 0};
        wf[0][g][0] = (hi < 2) ? ldwf(eWih0, 16, n, (hi & 1) * 8) : z;  // K=16, zero-pad k>=16
        wf[0][g][1] = z;                  // dead in enc (DCE'd); dec overwrites
        #pragma unroll
        for (int kk = 0; kk < 2; ++kk) {
            wf[1][g][kk] = ldwf(eWhh0, 64, n, kk * 32 + hi * 8);
            wf[2][g][kk] = ldwf(eWih1, 64, n, kk * 32 + hi * 8);
            wf[3][g][kk] = ldwf(eWhh1, 64, n, kk * 32 + hi * 8);
        }
        bz0[g] = eb0[g * 64 + w * 16 + lo];
        bz1[g] = eb1[g * 64 + w * 16 + lo];
    }

    float c0[4] = {0.f, 0.f, 0.f, 0.f};
    float c1[4] = {0.f, 0.f, 0.f, 0.f};
    __syncthreads();   // staging zeros visible

    const float* xb = X + (size_t)(wg * 16 + lo) * 1536 + (hi & 1) * 8;

    // ================= encoder (ONE barrier per step) =================
    #pragma unroll 2
    for (int t = 0; t < 96; ++t) {
        const int pw = t & 1, pr = pw ^ 1;
        // issue x loads at top: latency hides under h ds_reads + h-MFMAs
        const float* p = xb + t * 16;
        const float4 xv0 = *(const float4*)p;
        const float4 xv1 = *(const float4*)(p + 4);
        v4f acc[4];
        // ---- layer 0: z = h0@Whh0^T (first) + x_t@Wih0^T + b0 ----
        #pragma unroll
        for (int g = 0; g < 4; ++g)
            acc[g] = (v4f){bz0[g], bz0[g], bz0[g], bz0[g]};
        #pragma unroll
        for (int kk = 0; kk < 2; ++kk) {
            const v8s ah = *(const v8s*)&sh0[pr][kk * 512 + lane * 8];
            #pragma unroll
            for (int g = 0; g < 4; ++g) acc[g] = mfma(ah, wf[1][g][kk], acc[g]);
        }
        {
            const v8s ax = pack8(xv0, xv1);
            #pragma unroll
            for (int g = 0; g < 4; ++g) acc[g] = mfma(ax, wf[0][g][0], acc[g]);
        }
        {
            float hh[4];
            #pragma unroll
            for (int q = 0; q < 4; ++q)
                hh[q] = cell(acc[0][q], acc[1][q], acc[2][q], acc[3][q], c0[q]);
            #pragma unroll
            for (int qp = 0; qp < 2; ++qp) {
                unsigned pk = cvtpk(hh[2 * qp], hh[2 * qp + 1]);
                short* b = &sh0[pw][wsidx + qp * 16];
                b[0] = (short)pk; b[8] = (short)(pk >> 16);
            }
        }
        __syncthreads();
        // ---- layer 1: z = h0@Wih1^T + h1@Whh1^T + b1 ----
        #pragma unroll
        for (int g = 0; g < 4; ++g)
            acc[g] = (v4f){bz1[g], bz1[g], bz1[g], bz1[g]};
        #pragma unroll
        for (int kk = 0; kk < 2; ++kk) {
            const v8s ah = *(const v8s*)&sh0[pw][kk * 512 + lane * 8];
            const v8s bh = *(const v8s*)&sh1[pr][kk * 512 + lane * 8];
            #pragma unroll
            for (int g = 0; g < 4; ++g) {
                acc[g] = mfma(ah, wf[2][g][kk], acc[g]);
                acc[g] = mfma(bh, wf[3][g][kk], acc[g]);
            }
        }
        {
            float hh[4];
            #pragma unroll
            for (int q = 0; q < 4; ++q)
                hh[q] = cell(acc[0][q], acc[1][q], acc[2][q], acc[3][q], c1[q]);
            #pragma unroll
            for (int qp = 0; qp < 2; ++qp) {
                unsigned pk = cvtpk(hh[2 * qp], hh[2 * qp + 1]);
                short* b = &sh1[pw][wsidx + qp * 16];
                b[0] = (short)pk; b[8] = (short)(pk >> 16);
            }
        }
        // no second barrier: next l0 writes sh0[pr] (disjoint from sh0[pw]/sh1[*]
        // read in l1); all cross-wave producer->consumer pairs are ordered by the
        // mid-step barrier of the following step.
    }
    __syncthreads();   // order enc t=95 l1 writes (sh1[1]) before dec s=0 reads
    // finals: h0 in sh0[1], h1 in sh1[1]

    // ---- decoder + head weights -> registers ----
    #pragma unroll
    for (int g = 0; g < 4; ++g) {
        const int n = (w + 4 * g) * 16 + lo;
        #pragma unroll
        for (int kk = 0; kk < 2; ++kk) {
            wf[0][g][kk] = ldwf(dWih0, 64, n, kk * 32 + hi * 8);
            wf[1][g][kk] = ldwf(dWhh0, 64, n, kk * 32 + hi * 8);
            wf[2][g][kk] = ldwf(dWih1, 64, n, kk * 32 + hi * 8);
            wf[3][g][kk] = ldwf(dWhh1, 64, n, kk * 32 + hi * 8);
        }
        bz0[g] = db0[g * 64 + w * 16 + lo];
        bz1[g] = db1[g * 64 + w * 16 + lo];
    }
    v8s w1f[2], w2f[2];
    #pragma unroll
    for (int kk = 0; kk < 2; ++kk) {
        w1f[kk] = ldwf(rW1, 64, w * 16 + lo, kk * 32 + hi * 8);
        w2f[kk] = ldwf(rW2, 64, lo, kk * 32 + hi * 8);
    }
    const float hb1 = rb1[w * 16 + lo];
    const float hb2 = rb2[lo];
    float lb[4];
    #pragma unroll
    for (int q = 0; q < 4; ++q) {
        lb[q] = bias[(size_t)(wg * 16 + hi * 4 + q) * 16 + lo];
        c0[q] = 0.f;
        c1[q] = 0.f;
    }

    // ================= decoder (TWO barriers per step; head GEMM2 pipelined) ====
    // sy1 single-buffered: GEMM1(s) writes post-bar2(s); GEMM2(s) reads post-bar1(s+1)
    // (ordered by bar2(s)..bar1(s+1)); GEMM1(s+1) overwrites post-bar2(s+1) (ordered).
    #pragma unroll 2
    for (int s = 0; s < 24; ++s) {
        const int pw = s & 1, pr = pw ^ 1;   // s=0 reads parity 1 = encoder finals
        v4f acc[4];
        // ---- dec layer 0: x = h_t (sh1[pr]), hidden = dh0 (sh0[pr]) -> sh0[pw] ----
        #pragma unroll
        for (int g = 0; g < 4; ++g)
            acc[g] = (v4f){bz0[g], bz0[g], bz0[g], bz0[g]};
        #pragma unroll
        for (int kk = 0; kk < 2; ++kk) {
            const v8s ah = *(const v8s*)&sh1[pr][kk * 512 + lane * 8];
            const v8s bh = *(const v8s*)&sh0[pr][kk * 512 + lane * 8];
            #pragma unroll
            for (int g = 0; g < 4; ++g) {
                acc[g] = mfma(ah, wf[0][g][kk], acc[g]);
                acc[g] = mfma(bh, wf[1][g][kk], acc[g]);
            }
        }
        {
            float hh[4];
            #pragma unroll
            for (int q = 0; q < 4; ++q)
                hh[q] = cell(acc[0][q], acc[1][q], acc[2][q], acc[3][q], c0[q]);
            #pragma unroll
            for (int qp = 0; qp < 2; ++qp) {
                unsigned pk = cvtpk(hh[2 * qp], hh[2 * qp + 1]);
                short* b = &sh0[pw][wsidx + qp * 16];
                b[0] = (short)pk; b[8] = (short)(pk >> 16);
            }
        }
        __syncthreads();                      // bar1: h0 ready; also orders GEMM1(s-1)->GEMM2(s-1)
        // ---- head GEMM2 for step s-1 (wave 0 only), overlaps l1 of other waves ----
        if (w == 0 && s > 0) {
            v4f a2 = (v4f){hb2, hb2, hb2, hb2};
            #pragma unroll
            for (int kk = 0; kk < 2; ++kk) {
                const v8s a = *(const v8s*)&sy1[kk * 512 + lane * 8];
                a2 = mfma(a, w2f[kk], a2);
            }
            #pragma unroll
            for (int q = 0; q < 4; ++q) {
                size_t row = (size_t)(wg * 16 + hi * 4 + q);
                out[row * 384 + (s - 1) * 16 + lo] = a2[q] + lb[q];
            }
        }
        // ---- dec layer 1: x = sh0[pw], hidden = dh1 (sh1[pr]) -> sh1[pw] ----
        #pragma unroll
        for (int g = 0; g < 4; ++g)
            acc[g] = (v4f){bz1[g], bz1[g], bz1[g], bz1[g]};
        #pragma unroll
        for (int kk = 0; kk < 2; ++kk) {
            const v8s ah = *(const v8s*)&sh0[pw][kk * 512 + lane * 8];
            const v8s bh = *(const v8s*)&sh1[pr][kk * 512 + lane * 8];
            #pragma unroll
            for (int g = 0; g < 4; ++g) {
                acc[g] = mfma(ah, wf[2][g][kk], acc[g]);
                acc[g] = mfma(bh, wf[3][g][kk], acc[g]);
            }
        }
        {
            float hh[4];
            #pragma unroll
            for (int q = 0; q < 4; ++q)
                hh[q] = cell(acc[0][q], acc[1][q], acc[2][q], acc[3][q], c1[q]);
            #pragma unroll
            for (int qp = 0; qp < 2; ++qp) {
                unsigned pk = cvtpk(hh[2 * qp], hh[2 * qp + 1]);
                short* b = &sh1[pw][wsidx + qp * 16];
                b[0] = (short)pk; b[8] = (short)(pk >> 16);
            }
        }
        __syncthreads();                      // bar2: h1 ready (GEMM1 + next-step l0)
        // ---- head GEMM1: y1 = relu(h_t @ W1^T + b1), Ntile = w; no barrier after ----
        v4f ay = (v4f){hb1, hb1, hb1, hb1};
        #pragma unroll
        for (int kk = 0; kk < 2; ++kk) {
            const v8s ah = *(const v8s*)&sh1[pw][kk * 512 + lane * 8];
            ay = mfma(ah, w1f[kk], ay);
        }
        #pragma unroll
        for (int qp = 0; qp < 2; ++qp) {
            unsigned pk = cvtpk(fmaxf(ay[2 * qp], 0.f), fmaxf(ay[2 * qp + 1], 0.f));
            short* b = &sy1[wsidx + qp * 16];
            b[0] = (short)pk; b[8] = (short)(pk >> 16);
        }
    }
    // ---- drain: head GEMM2 for s=23 ----
    __syncthreads();
    if (w == 0) {
        v4f a2 = (v4f){hb2, hb2, hb2, hb2};
        #pragma unroll
        for (int kk = 0; kk < 2; ++kk) {
            const v8s a = *(const v8s*)&sy1[kk * 512 + lane * 8];
            a2 = mfma(a, w2f[kk], a2);
        }
        #pragma unroll
        for (int q = 0; q < 4; ++q) {
            size_t row = (size_t)(wg * 16 + hi * 4 + q);
            out[row * 384 + 23 * 16 + lo] = a2[q] + lb[q];
        }
    }
}

extern "C" void kernel_launch(void* const* d_in, const int* in_sizes, int n_in,
                              void* d_out, int out_size, void* d_ws, size_t ws_size,
                              hipStream_t stream) {
    seq2seq<<<dim3(1024), dim3(256), 0, stream>>>(
        (const float*)d_in[0],   // X
        (const float*)d_in[1],   // bias   (d_in[2] = X_mask, unused by reference)
        (const float*)d_in[3],  (const float*)d_in[4],  (const float*)d_in[5],
        (const float*)d_in[6],  (const float*)d_in[7],  (const float*)d_in[8],
        (const float*)d_in[9],  (const float*)d_in[10], (const float*)d_in[11],
        (const float*)d_in[12], (const float*)d_in[13], (const float*)d_in[14],
        (const float*)d_in[15], (const float*)d_in[16],
        (const float*)d_in[17], (const float*)d_in[18],
        (float*)d_out);
}

// Round 7
// 968.425 us; speedup vs baseline: 1.2402x; 1.2402x over previous
//
#include <hip/hip_runtime.h>

typedef short v8s __attribute__((ext_vector_type(8)));   // 8 x bf16 (4 VGPR)
typedef float v4f __attribute__((ext_vector_type(4)));

// HW packed f32->bf16 (RNE), 2 elems/instr. No builtin on gfx950 -> inline asm.
__device__ __forceinline__ unsigned cvtpk(float lo, float hi) {
    unsigned r;
    asm("v_cvt_pk_bf16_f32 %0, %1, %2" : "=v"(r) : "v"(lo), "v"(hi));
    return r;
}
__device__ __forceinline__ v8s pack8(float4 f0, float4 f1) {
    union { unsigned u[4]; v8s v; } r;
    r.u[0] = cvtpk(f0.x, f0.y); r.u[1] = cvtpk(f0.z, f0.w);
    r.u[2] = cvtpk(f1.x, f1.y); r.u[3] = cvtpk(f1.z, f1.w);
    return r.v;
}
__device__ __forceinline__ v4f mfma(v8s a, v8s b, v4f c) {
    return __builtin_amdgcn_mfma_f32_16x16x32_bf16(a, b, c, 0, 0, 0);
}
// B-frag for Z = Xin @ W^T from f32 W: lane holds W[n][k0..k0+7] as bf16.
__device__ __forceinline__ v8s ldwf(const float* W, int rowElems, int n, int k0) {
    const float* p = W + (size_t)n * rowElems + k0;
    union { unsigned u[4]; v8s v; } r;
    #pragma unroll
    for (int j = 0; j < 4; ++j) r.u[j] = cvtpk(p[2 * j], p[2 * j + 1]);
    return r.v;
}

// Fused-denominator LSTM cell: 5 exp2 + 2 rcp. (verified R3-R6, absmax 0.015625)
__device__ __forceinline__ float cell(float zi, float zf, float zg, float zo, float& c) {
    const float NL = -1.44269504f, PG = 2.88539008f;
    float ei = __builtin_amdgcn_exp2f(NL * zi);
    float ef = __builtin_amdgcn_exp2f(NL * zf);
    float eg = __builtin_amdgcn_exp2f(PG * zg);
    float Df = 1.f + ef;
    float Dig = (1.f + ei) * (1.f + eg);
    float cc = (c * Dig + Df * (eg - 1.f)) * __builtin_amdgcn_rcpf(Df * Dig);
    c = cc;
    float eo = __builtin_amdgcn_exp2f(NL * zo);
    float ec = __builtin_amdgcn_exp2f(fminf(PG * cc, 60.f));
    return (ec - 1.f) * __builtin_amdgcn_rcpf((1.f + eo) * (1.f + ec));
}

// ===========================================================================
// ENCODER kernel. Live set ~166 regs (28 weight frags, no head weights) ->
// (256,3)'s 170-reg budget should fit WITHOUT spills (R6's spills came from
// the decoder phase's ~190-reg peak, now excised). Spill tripwire: FETCH.
// ===========================================================================
__global__ __launch_bounds__(256, 3) void seq2seq_enc(
    const float* __restrict__ X,
    const float* __restrict__ eWih0, const float* __restrict__ eWhh0, const float* __restrict__ eb0,
    const float* __restrict__ eWih1, const float* __restrict__ eWhh1, const float* __restrict__ eb1,
    unsigned* __restrict__ ws)
{
    __shared__ __align__(16) short sh0[2][1024];
    __shared__ __align__(16) short sh1[2][1024];

    const int tid  = threadIdx.x;
    const int lane = tid & 63;
    const int w    = tid >> 6;
    const int lo   = lane & 15, hi = lane >> 4;
    const int wg   = blockIdx.x;          // 16 batch rows per block

    for (int i = tid; i < 512; i += 256) {
        ((int*)sh0)[512 + i] = 0;
        ((int*)sh1)[512 + i] = 0;
    }
    const int wsidx = (w >> 1) * 512 + (((2 * w) + (lo >> 3)) & 3) * 128 + hi * 32 + (lo & 7);

    // weights: explicit arrays, no dead [kk=1] slot for Wih0 (saves 16 regs vs wf[4][4][2])
    v8s wx[4], wh[4][2], wi1[4][2], wh1[4][2];
    float bz0[4], bz1[4];
    #pragma unroll
    for (int g = 0; g < 4; ++g) {
        const int n = (w + 4 * g) * 16 + lo;
        v8s z = {0, 0, 0, 0, 0, 0, 0, 0};
        wx[g] = (hi < 2) ? ldwf(eWih0, 16, n, (hi & 1) * 8) : z;   // K=16 zero-pad
        #pragma unroll
        for (int kk = 0; kk < 2; ++kk) {
            wh[g][kk]  = ldwf(eWhh0, 64, n, kk * 32 + hi * 8);
            wi1[g][kk] = ldwf(eWih1, 64, n, kk * 32 + hi * 8);
            wh1[g][kk] = ldwf(eWhh1, 64, n, kk * 32 + hi * 8);
        }
        bz0[g] = eb0[g * 64 + w * 16 + lo];
        bz1[g] = eb1[g * 64 + w * 16 + lo];
    }

    float c0[4] = {0.f, 0.f, 0.f, 0.f};
    float c1[4] = {0.f, 0.f, 0.f, 0.f};
    __syncthreads();

    const float* xb = X + (size_t)(wg * 16 + lo) * 1536 + (hi & 1) * 8;

    #pragma unroll 2
    for (int t = 0; t < 96; ++t) {
        const int pw = t & 1, pr = pw ^ 1;
        const float* p = xb + t * 16;
        const float4 xv0 = *(const float4*)p;
        const float4 xv1 = *(const float4*)(p + 4);
        v4f acc[4];
        // layer 0
        #pragma unroll
        for (int g = 0; g < 4; ++g)
            acc[g] = (v4f){bz0[g], bz0[g], bz0[g], bz0[g]};
        #pragma unroll
        for (int kk = 0; kk < 2; ++kk) {
            const v8s ah = *(const v8s*)&sh0[pr][kk * 512 + lane * 8];
            #pragma unroll
            for (int g = 0; g < 4; ++g) acc[g] = mfma(ah, wh[g][kk], acc[g]);
        }
        {
            const v8s ax = pack8(xv0, xv1);
            #pragma unroll
            for (int g = 0; g < 4; ++g) acc[g] = mfma(ax, wx[g], acc[g]);
        }
        {
            float hh[4];
            #pragma unroll
            for (int q = 0; q < 4; ++q)
                hh[q] = cell(acc[0][q], acc[1][q], acc[2][q], acc[3][q], c0[q]);
            #pragma unroll
            for (int qp = 0; qp < 2; ++qp) {
                unsigned pk = cvtpk(hh[2 * qp], hh[2 * qp + 1]);
                short* b = &sh0[pw][wsidx + qp * 16];
                b[0] = (short)pk; b[8] = (short)(pk >> 16);
            }
        }
        __syncthreads();
        // layer 1
        #pragma unroll
        for (int g = 0; g < 4; ++g)
            acc[g] = (v4f){bz1[g], bz1[g], bz1[g], bz1[g]};
        #pragma unroll
        for (int kk = 0; kk < 2; ++kk) {
            const v8s ah = *(const v8s*)&sh0[pw][kk * 512 + lane * 8];
            const v8s bh = *(const v8s*)&sh1[pr][kk * 512 + lane * 8];
            #pragma unroll
            for (int g = 0; g < 4; ++g) {
                acc[g] = mfma(ah, wi1[g][kk], acc[g]);
                acc[g] = mfma(bh, wh1[g][kk], acc[g]);
            }
        }
        {
            float hh[4];
            #pragma unroll
            for (int q = 0; q < 4; ++q)
                hh[q] = cell(acc[0][q], acc[1][q], acc[2][q], acc[3][q], c1[q]);
            #pragma unroll
            for (int qp = 0; qp < 2; ++qp) {
                unsigned pk = cvtpk(hh[2 * qp], hh[2 * qp + 1]);
                short* b = &sh1[pw][wsidx + qp * 16];
                b[0] = (short)pk; b[8] = (short)(pk >> 16);
            }
        }
        // no second barrier (same hazard proof as R4)
    }
    __syncthreads();   // t=95 writes visible block-wide
    // finals (parity 1) -> workspace, exact bf16 bits. 4 KB/block.
    unsigned* wsb = ws + (size_t)wg * 1024;
    wsb[tid]       = ((const unsigned*)sh0)[512 + tid];
    wsb[256 + tid] = ((const unsigned*)sh0)[768 + tid];
    wsb[512 + tid] = ((const unsigned*)sh1)[512 + tid];
    wsb[768 + tid] = ((const unsigned*)sh1)[768 + tid];
}

// ===========================================================================
// DECODER kernel: R4's decoder verbatim, reading finals from ws. (256,2).
// ===========================================================================
__global__ __launch_bounds__(256, 2) void seq2seq_dec(
    const unsigned* __restrict__ ws,
    const float* __restrict__ bias,
    const float* __restrict__ dWih0, const float* __restrict__ dWhh0, const float* __restrict__ db0,
    const float* __restrict__ dWih1, const float* __restrict__ dWhh1, const float* __restrict__ db1,
    const float* __restrict__ rW1, const float* __restrict__ rb1,
    const float* __restrict__ rW2, const float* __restrict__ rb2,
    float* __restrict__ out)
{
    __shared__ __align__(16) short sh0[2][1024];
    __shared__ __align__(16) short sh1[2][1024];
    __shared__ __align__(16) short sy1[1024];

    const int tid  = threadIdx.x;
    const int lane = tid & 63;
    const int w    = tid >> 6;
    const int lo   = lane & 15, hi = lane >> 4;
    const int wg   = blockIdx.x;

    // restore encoder finals into parity 1
    const unsigned* wsb = ws + (size_t)wg * 1024;
    ((unsigned*)sh0)[512 + tid] = wsb[tid];
    ((unsigned*)sh0)[768 + tid] = wsb[256 + tid];
    ((unsigned*)sh1)[512 + tid] = wsb[512 + tid];
    ((unsigned*)sh1)[768 + tid] = wsb[768 + tid];

    const int wsidx = (w >> 1) * 512 + (((2 * w) + (lo >> 3)) & 3) * 128 + hi * 32 + (lo & 7);

    v8s wf[4][4][2];
    float bz0[4], bz1[4];
    #pragma unroll
    for (int g = 0; g < 4; ++g) {
        const int n = (w + 4 * g) * 16 + lo;
        #pragma unroll
        for (int kk = 0; kk < 2; ++kk) {
            wf[0][g][kk] = ldwf(dWih0, 64, n, kk * 32 + hi * 8);
            wf[1][g][kk] = ldwf(dWhh0, 64, n, kk * 32 + hi * 8);
            wf[2][g][kk] = ldwf(dWih1, 64, n, kk * 32 + hi * 8);
            wf[3][g][kk] = ldwf(dWhh1, 64, n, kk * 32 + hi * 8);
        }
        bz0[g] = db0[g * 64 + w * 16 + lo];
        bz1[g] = db1[g * 64 + w * 16 + lo];
    }
    v8s w1f[2], w2f[2];
    #pragma unroll
    for (int kk = 0; kk < 2; ++kk) {
        w1f[kk] = ldwf(rW1, 64, w * 16 + lo, kk * 32 + hi * 8);
        w2f[kk] = ldwf(rW2, 64, lo, kk * 32 + hi * 8);
    }
    const float hb1 = rb1[w * 16 + lo];
    const float hb2 = rb2[lo];
    float lb[4];
    float c0[4], c1[4];
    #pragma unroll
    for (int q = 0; q < 4; ++q) {
        lb[q] = bias[(size_t)(wg * 16 + hi * 4 + q) * 16 + lo];
        c0[q] = 0.f;
        c1[q] = 0.f;
    }
    __syncthreads();   // finals staged

    #pragma unroll 2
    for (int s = 0; s < 24; ++s) {
        const int pw = s & 1, pr = pw ^ 1;   // s=0 reads parity 1 = encoder finals
        v4f acc[4];
        // dec layer 0
        #pragma unroll
        for (int g = 0; g < 4; ++g)
            acc[g] = (v4f){bz0[g], bz0[g], bz0[g], bz0[g]};
        #pragma unroll
        for (int kk = 0; kk < 2; ++kk) {
            const v8s ah = *(const v8s*)&sh1[pr][kk * 512 + lane * 8];
            const v8s bh = *(const v8s*)&sh0[pr][kk * 512 + lane * 8];
            #pragma unroll
            for (int g = 0; g < 4; ++g) {
                acc[g] = mfma(ah, wf[0][g][kk], acc[g]);
                acc[g] = mfma(bh, wf[1][g][kk], acc[g]);
            }
        }
        {
            float hh[4];
            #pragma unroll
            for (int q = 0; q < 4; ++q)
                hh[q] = cell(acc[0][q], acc[1][q], acc[2][q], acc[3][q], c0[q]);
            #pragma unroll
            for (int qp = 0; qp < 2; ++qp) {
                unsigned pk = cvtpk(hh[2 * qp], hh[2 * qp + 1]);
                short* b = &sh0[pw][wsidx + qp * 16];
                b[0] = (short)pk; b[8] = (short)(pk >> 16);
            }
        }
        __syncthreads();                      // bar1
        if (w == 0 && s > 0) {                // head GEMM2 for s-1, overlaps l1
            v4f a2 = (v4f){hb2, hb2, hb2, hb2};
            #pragma unroll
            for (int kk = 0; kk < 2; ++kk) {
                const v8s a = *(const v8s*)&sy1[kk * 512 + lane * 8];
                a2 = mfma(a, w2f[kk], a2);
            }
            #pragma unroll
            for (int q = 0; q < 4; ++q) {
                size_t row = (size_t)(wg * 16 + hi * 4 + q);
                out[row * 384 + (s - 1) * 16 + lo] = a2[q] + lb[q];
            }
        }
        // dec layer 1
        #pragma unroll
        for (int g = 0; g < 4; ++g)
            acc[g] = (v4f){bz1[g], bz1[g], bz1[g], bz1[g]};
        #pragma unroll
        for (int kk = 0; kk < 2; ++kk) {
            const v8s ah = *(const v8s*)&sh0[pw][kk * 512 + lane * 8];
            const v8s bh = *(const v8s*)&sh1[pr][kk * 512 + lane * 8];
            #pragma unroll
            for (int g = 0; g < 4; ++g) {
                acc[g] = mfma(ah, wf[2][g][kk], acc[g]);
                acc[g] = mfma(bh, wf[3][g][kk], acc[g]);
            }
        }
        {
            float hh[4];
            #pragma unroll
            for (int q = 0; q < 4; ++q)
                hh[q] = cell(acc[0][q], acc[1][q], acc[2][q], acc[3][q], c1[q]);
            #pragma unroll
            for (int qp = 0; qp < 2; ++qp) {
                unsigned pk = cvtpk(hh[2 * qp], hh[2 * qp + 1]);
                short* b = &sh1[pw][wsidx + qp * 16];
                b[0] = (short)pk; b[8] = (short)(pk >> 16);
            }
        }
        __syncthreads();                      // bar2
        // head GEMM1
        v4f ay = (v4f){hb1, hb1, hb1, hb1};
        #pragma unroll
        for (int kk = 0; kk < 2; ++kk) {
            const v8s ah = *(const v8s*)&sh1[pw][kk * 512 + lane * 8];
            ay = mfma(ah, w1f[kk], ay);
        }
        #pragma unroll
        for (int qp = 0; qp < 2; ++qp) {
            unsigned pk = cvtpk(fmaxf(ay[2 * qp], 0.f), fmaxf(ay[2 * qp + 1], 0.f));
            short* b = &sy1[wsidx + qp * 16];
            b[0] = (short)pk; b[8] = (short)(pk >> 16);
        }
    }
    __syncthreads();
    if (w == 0) {                             // drain GEMM2 s=23
        v4f a2 = (v4f){hb2, hb2, hb2, hb2};
        #pragma unroll
        for (int kk = 0; kk < 2; ++kk) {
            const v8s a = *(const v8s*)&sy1[kk * 512 + lane * 8];
            a2 = mfma(a, w2f[kk], a2);
        }
        #pragma unroll
        for (int q = 0; q < 4; ++q) {
            size_t row = (size_t)(wg * 16 + hi * 4 + q);
            out[row * 384 + 23 * 16 + lo] = a2[q] + lb[q];
        }
    }
}

// ===========================================================================
// Monolithic fallback (R4 verbatim) if ws is too small.
// ===========================================================================
__global__ __launch_bounds__(256, 2) void seq2seq_mono(
    const float* __restrict__ X,
    const float* __restrict__ bias,
    const float* __restrict__ eWih0, const float* __restrict__ eWhh0, const float* __restrict__ eb0,
    const float* __restrict__ eWih1, const float* __restrict__ eWhh1, const float* __restrict__ eb1,
    const float* __restrict__ dWih0, const float* __restrict__ dWhh0, const float* __restrict__ db0,
    const float* __restrict__ dWih1, const float* __restrict__ dWhh1, const float* __restrict__ db1,
    const float* __restrict__ rW1, const float* __restrict__ rb1,
    const float* __restrict__ rW2, const float* __restrict__ rb2,
    float* __restrict__ out)
{
    __shared__ __align__(16) short sh0[2][1024];
    __shared__ __align__(16) short sh1[2][1024];
    __shared__ __align__(16) short sy1[1024];

    const int tid  = threadIdx.x;
    const int lane = tid & 63;
    const int w    = tid >> 6;
    const int lo   = lane & 15, hi = lane >> 4;
    const int wg   = blockIdx.x;

    for (int i = tid; i < 512; i += 256) {
        ((int*)sh0)[512 + i] = 0;
        ((int*)sh1)[512 + i] = 0;
    }
    const int wsidx = (w >> 1) * 512 + (((2 * w) + (lo >> 3)) & 3) * 128 + hi * 32 + (lo & 7);

    v8s wf[4][4][2];
    float bz0[4], bz1[4];
    #pragma unroll
    for (int g = 0; g < 4; ++g) {
        const int n = (w + 4 * g) * 16 + lo;
        v8s z = {0, 0, 0, 0, 0, 0, 0, 0};
        wf[0][g][0] = (hi < 2) ? ldwf(eWih0, 16, n, (hi & 1) * 8) : z;
        wf[0][g][1] = z;
        #pragma unroll
        for (int kk = 0; kk < 2; ++kk) {
            wf[1][g][kk] = ldwf(eWhh0, 64, n, kk * 32 + hi * 8);
            wf[2][g][kk] = ldwf(eWih1, 64, n, kk * 32 + hi * 8);
            wf[3][g][kk] = ldwf(eWhh1, 64, n, kk * 32 + hi * 8);
        }
        bz0[g] = eb0[g * 64 + w * 16 + lo];
        bz1[g] = eb1[g * 64 + w * 16 + lo];
    }
    float c0[4] = {0.f, 0.f, 0.f, 0.f};
    float c1[4] = {0.f, 0.f, 0.f, 0.f};
    __syncthreads();
    const float* xb = X + (size_t)(wg * 16 + lo) * 1536 + (hi & 1) * 8;

    #pragma unroll 2
    for (int t = 0; t < 96; ++t) {
        const int pw = t & 1, pr = pw ^ 1;
        const float* p = xb + t * 16;
        const float4 xv0 = *(const float4*)p;
        const float4 xv1 = *(const float4*)(p + 4);
        v4f acc[4];
        #pragma unroll
        for (int g = 0; g < 4; ++g)
            acc[g] = (v4f){bz0[g], bz0[g], bz0[g], bz0[g]};
        #pragma unroll
        for (int kk = 0; kk < 2; ++kk) {
            const v8s ah = *(const v8s*)&sh0[pr][kk * 512 + lane * 8];
            #pragma unroll
            for (int g = 0; g < 4; ++g) acc[g] = mfma(ah, wf[1][g][kk], acc[g]);
        }
        {
            const v8s ax = pack8(xv0, xv1);
            #pragma unroll
            for (int g = 0; g < 4; ++g) acc[g] = mfma(ax, wf[0][g][0], acc[g]);
        }
        {
            float hh[4];
            #pragma unroll
            for (int q = 0; q < 4; ++q)
                hh[q] = cell(acc[0][q], acc[1][q], acc[2][q], acc[3][q], c0[q]);
            #pragma unroll
            for (int qp = 0; qp < 2; ++qp) {
                unsigned pk = cvtpk(hh[2 * qp], hh[2 * qp + 1]);
                short* b = &sh0[pw][wsidx + qp * 16];
                b[0] = (short)pk; b[8] = (short)(pk >> 16);
            }
        }
        __syncthreads();
        #pragma unroll
        for (int g = 0; g < 4; ++g)
            acc[g] = (v4f){bz1[g], bz1[g], bz1[g], bz1[g]};
        #pragma unroll
        for (int kk = 0; kk < 2; ++kk) {
            const v8s ah = *(const v8s*)&sh0[pw][kk * 512 + lane * 8];
            const v8s bh = *(const v8s*)&sh1[pr][kk * 512 + lane * 8];
            #pragma unroll
            for (int g = 0; g < 4; ++g) {
                acc[g] = mfma(ah, wf[2][g][kk], acc[g]);
                acc[g] = mfma(bh, wf[3][g][kk], acc[g]);
            }
        }
        {
            float hh[4];
            #pragma unroll
            for (int q = 0; q < 4; ++q)
                hh[q] = cell(acc[0][q], acc[1][q], acc[2][q], acc[3][q], c1[q]);
            #pragma unroll
            for (int qp = 0; qp < 2; ++qp) {
                unsigned pk = cvtpk(hh[2 * qp], hh[2 * qp + 1]);
                short* b = &sh1[pw][wsidx + qp * 16];
                b[0] = (short)pk; b[8] = (short)(pk >> 16);
            }
        }
    }
    __syncthreads();

    #pragma unroll
    for (int g = 0; g < 4; ++g) {
        const int n = (w + 4 * g) * 16 + lo;
        #pragma unroll
        for (int kk = 0; kk < 2; ++kk) {
            wf[0][g][kk] = ldwf(dWih0, 64, n, kk * 32 + hi * 8);
            wf[1][g][kk] = ldwf(dWhh0, 64, n, kk * 32 + hi * 8);
            wf[2][g][kk] = ldwf(dWih1, 64, n, kk * 32 + hi * 8);
            wf[3][g][kk] = ldwf(dWhh1, 64, n, kk * 32 + hi * 8);
        }
        bz0[g] = db0[g * 64 + w * 16 + lo];
        bz1[g] = db1[g * 64 + w * 16 + lo];
    }
    v8s w1f[2], w2f[2];
    #pragma unroll
    for (int kk = 0; kk < 2; ++kk) {
        w1f[kk] = ldwf(rW1, 64, w * 16 + lo, kk * 32 + hi * 8);
        w2f[kk] = ldwf(rW2, 64, lo, kk * 32 + hi * 8);
    }
    const float hb1 = rb1[w * 16 + lo];
    const float hb2 = rb2[lo];
    float lb[4];
    #pragma unroll
    for (int q = 0; q < 4; ++q) {
        lb[q] = bias[(size_t)(wg * 16 + hi * 4 + q) * 16 + lo];
        c0[q] = 0.f;
        c1[q] = 0.f;
    }

    #pragma unroll 2
    for (int s = 0; s < 24; ++s) {
        const int pw = s & 1, pr = pw ^ 1;
        v4f acc[4];
        #pragma unroll
        for (int g = 0; g < 4; ++g)
            acc[g] = (v4f){bz0[g], bz0[g], bz0[g], bz0[g]};
        #pragma unroll
        for (int kk = 0; kk < 2; ++kk) {
            const v8s ah = *(const v8s*)&sh1[pr][kk * 512 + lane * 8];
            const v8s bh = *(const v8s*)&sh0[pr][kk * 512 + lane * 8];
            #pragma unroll
            for (int g = 0; g < 4; ++g) {
                acc[g] = mfma(ah, wf[0][g][kk], acc[g]);
                acc[g] = mfma(bh, wf[1][g][kk], acc[g]);
            }
        }
        {
            float hh[4];
            #pragma unroll
            for (int q = 0; q < 4; ++q)
                hh[q] = cell(acc[0][q], acc[1][q], acc[2][q], acc[3][q], c0[q]);
            #pragma unroll
            for (int qp = 0; qp < 2; ++qp) {
                unsigned pk = cvtpk(hh[2 * qp], hh[2 * qp + 1]);
                short* b = &sh0[pw][wsidx + qp * 16];
                b[0] = (short)pk; b[8] = (short)(pk >> 16);
            }
        }
        __syncthreads();
        if (w == 0 && s > 0) {
            v4f a2 = (v4f){hb2, hb2, hb2, hb2};
            #pragma unroll
            for (int kk = 0; kk < 2; ++kk) {
                const v8s a = *(const v8s*)&sy1[kk * 512 + lane * 8];
                a2 = mfma(a, w2f[kk], a2);
            }
            #pragma unroll
            for (int q = 0; q < 4; ++q) {
                size_t row = (size_t)(wg * 16 + hi * 4 + q);
                out[row * 384 + (s - 1) * 16 + lo] = a2[q] + lb[q];
            }
        }
        #pragma unroll
        for (int g = 0; g < 4; ++g)
            acc[g] = (v4f){bz1[g], bz1[g], bz1[g], bz1[g]};
        #pragma unroll
        for (int kk = 0; kk < 2; ++kk) {
            const v8s ah = *(const v8s*)&sh0[pw][kk * 512 + lane * 8];
            const v8s bh = *(const v8s*)&sh1[pr][kk * 512 + lane * 8];
            #pragma unroll
            for (int g = 0; g < 4; ++g) {
                acc[g] = mfma(ah, wf[2][g][kk], acc[g]);
                acc[g] = mfma(bh, wf[3][g][kk], acc[g]);
            }
        }
        {
            float hh[4];
            #pragma unroll
            for (int q = 0; q < 4; ++q)
                hh[q] = cell(acc[0][q], acc[1][q], acc[2][q], acc[3][q], c1[q]);
            #pragma unroll
            for (int qp = 0; qp < 2; ++qp) {
                unsigned pk = cvtpk(hh[2 * qp], hh[2 * qp + 1]);
                short* b = &sh1[pw][wsidx + qp * 16];
                b[0] = (short)pk; b[8] = (short)(pk >> 16);
            }
        }
        __syncthreads();
        v4f ay = (v4f){hb1, hb1, hb1, hb1};
        #pragma unroll
        for (int kk = 0; kk < 2; ++kk) {
            const v8s ah = *(const v8s*)&sh1[pw][kk * 512 + lane * 8];
            ay = mfma(ah, w1f[kk], ay);
        }
        #pragma unroll
        for (int qp = 0; qp < 2; ++qp) {
            unsigned pk = cvtpk(fmaxf(ay[2 * qp], 0.f), fmaxf(ay[2 * qp + 1], 0.f));
            short* b = &sy1[wsidx + qp * 16];
            b[0] = (short)pk; b[8] = (short)(pk >> 16);
        }
    }
    __syncthreads();
    if (w == 0) {
        v4f a2 = (v4f){hb2, hb2, hb2, hb2};
        #pragma unroll
        for (int kk = 0; kk < 2; ++kk) {
            const v8s a = *(const v8s*)&sy1[kk * 512 + lane * 8];
            a2 = mfma(a, w2f[kk], a2);
        }
        #pragma unroll
        for (int q = 0; q < 4; ++q) {
            size_t row = (size_t)(wg * 16 + hi * 4 + q);
            out[row * 384 + 23 * 16 + lo] = a2[q] + lb[q];
        }
    }
}

extern "C" void kernel_launch(void* const* d_in, const int* in_sizes, int n_in,
                              void* d_out, int out_size, void* d_ws, size_t ws_size,
                              hipStream_t stream) {
    if (ws_size >= (size_t)4 * 1024 * 1024 && d_ws != nullptr) {
        seq2seq_enc<<<dim3(1024), dim3(256), 0, stream>>>(
            (const float*)d_in[0],
            (const float*)d_in[3], (const float*)d_in[4], (const float*)d_in[5],
            (const float*)d_in[6], (const float*)d_in[7], (const float*)d_in[8],
            (unsigned*)d_ws);
        seq2seq_dec<<<dim3(1024), dim3(256), 0, stream>>>(
            (const unsigned*)d_ws,
            (const float*)d_in[1],
            (const float*)d_in[9],  (const float*)d_in[10], (const float*)d_in[11],
            (const float*)d_in[12], (const float*)d_in[13], (const float*)d_in[14],
            (const float*)d_in[15], (const float*)d_in[16],
            (const float*)d_in[17], (const float*)d_in[18],
            (float*)d_out);
    } else {
        seq2seq_mono<<<dim3(1024), dim3(256), 0, stream>>>(
            (const float*)d_in[0],
            (const float*)d_in[1],
            (const float*)d_in[3],  (const float*)d_in[4],  (const float*)d_in[5],
            (const float*)d_in[6],  (const float*)d_in[7],  (const float*)d_in[8],
            (const float*)d_in[9],  (const float*)d_in[10], (const float*)d_in[11],
            (const float*)d_in[12], (const float*)d_in[13], (const float*)d_in[14],
            (const float*)d_in[15], (const float*)d_in[16],
            (const float*)d_in[17], (const float*)d_in[18],
            (float*)d_out);
    }
}

// Round 8
// 551.242 us; speedup vs baseline: 2.1789x; 1.7568x over previous
//
#include <hip/hip_runtime.h>

typedef short v8s __attribute__((ext_vector_type(8)));   // 8 x bf16 (4 VGPR)
typedef float v4f __attribute__((ext_vector_type(4)));

// HW packed f32->bf16 (RNE), 2 elems/instr. No builtin on gfx950 -> inline asm.
__device__ __forceinline__ unsigned cvtpk(float lo, float hi) {
    unsigned r;
    asm("v_cvt_pk_bf16_f32 %0, %1, %2" : "=v"(r) : "v"(lo), "v"(hi));
    return r;
}
__device__ __forceinline__ v8s pack8(float4 f0, float4 f1) {
    union { unsigned u[4]; v8s v; } r;
    r.u[0] = cvtpk(f0.x, f0.y); r.u[1] = cvtpk(f0.z, f0.w);
    r.u[2] = cvtpk(f1.x, f1.y); r.u[3] = cvtpk(f1.z, f1.w);
    return r.v;
}
__device__ __forceinline__ v4f mfma(v8s a, v8s b, v4f c) {
    return __builtin_amdgcn_mfma_f32_16x16x32_bf16(a, b, c, 0, 0, 0);
}
// B-frag for Z = Xin @ W^T from f32 W: lane holds W[n][k0..k0+7] as bf16.
__device__ __forceinline__ v8s ldwf(const float* W, int rowElems, int n, int k0) {
    const float* p = W + (size_t)n * rowElems + k0;
    union { unsigned u[4]; v8s v; } r;
    #pragma unroll
    for (int j = 0; j < 4; ++j) r.u[j] = cvtpk(p[2 * j], p[2 * j + 1]);
    return r.v;
}

// Fused-denominator LSTM cell: 5 exp2 + 2 rcp. (verified R3-R7, absmax 0.015625)
__device__ __forceinline__ float cell(float zi, float zf, float zg, float zo, float& c) {
    const float NL = -1.44269504f, PG = 2.88539008f;
    float ei = __builtin_amdgcn_exp2f(NL * zi);
    float ef = __builtin_amdgcn_exp2f(NL * zf);
    float eg = __builtin_amdgcn_exp2f(PG * zg);
    float Df = 1.f + ef;
    float Dig = (1.f + ei) * (1.f + eg);
    float cc = (c * Dig + Df * (eg - 1.f)) * __builtin_amdgcn_rcpf(Df * Dig);
    c = cc;
    float eo = __builtin_amdgcn_exp2f(NL * zo);
    float ec = __builtin_amdgcn_exp2f(fminf(PG * cc, 60.f));
    return (ec - 1.f) * __builtin_amdgcn_rcpf((1.f + eo) * (1.f + ec));
}

// Occupancy is structurally 2 waves/SIMD (R1/R5/R6/R7: every >2-wave attempt
// spills). This version instead deepens per-phase ILP: encoder collapses to
// ONE phase/step computing l1(t) AND the pipelined l0(t+1) together (two
// independent cell chains + 28 MFMA between consecutive barriers).
__global__ __launch_bounds__(256, 2) void seq2seq(
    const float* __restrict__ X,
    const float* __restrict__ bias,
    const float* __restrict__ eWih0, const float* __restrict__ eWhh0, const float* __restrict__ eb0,
    const float* __restrict__ eWih1, const float* __restrict__ eWhh1, const float* __restrict__ eb1,
    const float* __restrict__ dWih0, const float* __restrict__ dWhh0, const float* __restrict__ db0,
    const float* __restrict__ dWih1, const float* __restrict__ dWhh1, const float* __restrict__ db1,
    const float* __restrict__ rW1, const float* __restrict__ rb1,
    const float* __restrict__ rW2, const float* __restrict__ rb2,
    float* __restrict__ out)
{
    // h staging, frag-linear: [slot][kk*512 + lane*8 + j], bf16 single-plane.
    __shared__ __align__(16) short sh0[2][1024];
    __shared__ __align__(16) short sh1[2][1024];
    __shared__ __align__(16) short sy1[1024];

    const int tid  = threadIdx.x;
    const int lane = tid & 63;
    const int w    = tid >> 6;            // unit-group 0..3 (units 16w..16w+15)
    const int lo   = lane & 15, hi = lane >> 4;
    const int wg   = blockIdx.x;          // 16 batch rows per block

    // zero sh1 slot 1 (= h1(-1)); sh0 needs no zeroing (prologue writes h0(0))
    for (int i = tid; i < 512; i += 256) ((int*)sh1)[512 + i] = 0;

    // staging write index for value (m = hi*4+q, u = 16w+lo):
    const int wsidx = (w >> 1) * 512 + (((2 * w) + (lo >> 3)) & 3) * 128 + hi * 32 + (lo & 7);

    // ---- encoder weights -> register B-frags (explicit arrays, no dead slots) ----
    v8s wx[4], wh[4][2], wi1[4][2], wh1[4][2];
    float bz0[4], bz1[4];
    #pragma unroll
    for (int g = 0; g < 4; ++g) {
        const int n = (w + 4 * g) * 16 + lo;       // z column (row of W)
        v8s z = {0, 0, 0, 0, 0, 0, 0, 0};
        wx[g] = (hi < 2) ? ldwf(eWih0, 16, n, (hi & 1) * 8) : z;   // K=16 zero-pad
        #pragma unroll
        for (int kk = 0; kk < 2; ++kk) {
            wh[g][kk]  = ldwf(eWhh0, 64, n, kk * 32 + hi * 8);
            wi1[g][kk] = ldwf(eWih1, 64, n, kk * 32 + hi * 8);
            wh1[g][kk] = ldwf(eWhh1, 64, n, kk * 32 + hi * 8);
        }
        bz0[g] = eb0[g * 64 + w * 16 + lo];
        bz1[g] = eb1[g * 64 + w * 16 + lo];
    }

    float c0[4] = {0.f, 0.f, 0.f, 0.f};
    float c1[4] = {0.f, 0.f, 0.f, 0.f};

    const float* xb = X + (size_t)(wg * 16 + lo) * 1536 + (hi & 1) * 8;

    // ---- enc prologue: h0(0) = cell(b0 + x(0)@Wih0^T) (h0(-1)=0 -> skip h-MFMAs)
    v4f acc0[4];
    {
        const v8s ax = pack8(*(const float4*)xb, *(const float4*)(xb + 4));
        #pragma unroll
        for (int g = 0; g < 4; ++g) {
            acc0[g] = (v4f){bz0[g], bz0[g], bz0[g], bz0[g]};
            acc0[g] = mfma(ax, wx[g], acc0[g]);
        }
        float hh[4];
        #pragma unroll
        for (int q = 0; q < 4; ++q)
            hh[q] = cell(acc0[0][q], acc0[1][q], acc0[2][q], acc0[3][q], c0[q]);
        #pragma unroll
        for (int qp = 0; qp < 2; ++qp) {
            unsigned pk = cvtpk(hh[2 * qp], hh[2 * qp + 1]);
            short* b = &sh0[0][wsidx + qp * 16];
            b[0] = (short)pk; b[8] = (short)(pk >> 16);
        }
    }
    __syncthreads();   // h0(0) + sh1 zeros visible

    // ================= encoder: ONE phase + ONE barrier per step ==============
    // phase(t): reads h0(t) [sh0[sA]] + h1(t-1) [sh1[sB]]; computes l1(t) AND
    // the pipelined l0(t+1); writes h1(t) -> sh1[sA], h0(t+1) -> sh0[sB].
    // Hazards: in-phase reads/writes hit disjoint slots; all cross-wave
    // producer->consumer pairs are separated by the phase barrier.
    #pragma unroll 2
    for (int t = 0; t < 96; ++t) {
        const int sA = t & 1, sB = sA ^ 1;
        const int tn = (t < 95) ? t + 1 : 95;       // clamp: t=95 result discarded
        const float* p = xb + tn * 16;
        const float4 xv0 = *(const float4*)p;       // issue early; hides under MFMAs
        const float4 xv1 = *(const float4*)(p + 4);
        v8s ah[2], bh[2];
        #pragma unroll
        for (int kk = 0; kk < 2; ++kk) {
            ah[kk] = *(const v8s*)&sh0[sA][kk * 512 + lane * 8];   // h0(t)
            bh[kk] = *(const v8s*)&sh1[sB][kk * 512 + lane * 8];   // h1(t-1)
        }
        // l1(t): 16 MFMA
        v4f acc1[4];
        #pragma unroll
        for (int g = 0; g < 4; ++g)
            acc1[g] = (v4f){bz1[g], bz1[g], bz1[g], bz1[g]};
        #pragma unroll
        for (int kk = 0; kk < 2; ++kk)
            #pragma unroll
            for (int g = 0; g < 4; ++g) {
                acc1[g] = mfma(ah[kk], wi1[g][kk], acc1[g]);
                acc1[g] = mfma(bh[kk], wh1[g][kk], acc1[g]);
            }
        // l0(t+1): 12 MFMA (reuses ah — zero extra LDS traffic)
        #pragma unroll
        for (int g = 0; g < 4; ++g)
            acc0[g] = (v4f){bz0[g], bz0[g], bz0[g], bz0[g]};
        #pragma unroll
        for (int kk = 0; kk < 2; ++kk)
            #pragma unroll
            for (int g = 0; g < 4; ++g) acc0[g] = mfma(ah[kk], wh[g][kk], acc0[g]);
        {
            const v8s ax = pack8(xv0, xv1);
            #pragma unroll
            for (int g = 0; g < 4; ++g) acc0[g] = mfma(ax, wx[g], acc0[g]);
        }
        // cells1 -> h1(t) -> sh1[sA]
        {
            float hh[4];
            #pragma unroll
            for (int q = 0; q < 4; ++q)
                hh[q] = cell(acc1[0][q], acc1[1][q], acc1[2][q], acc1[3][q], c1[q]);
            #pragma unroll
            for (int qp = 0; qp < 2; ++qp) {
                unsigned pk = cvtpk(hh[2 * qp], hh[2 * qp + 1]);
                short* b = &sh1[sA][wsidx + qp * 16];
                b[0] = (short)pk; b[8] = (short)(pk >> 16);
            }
        }
        // cells0 -> h0(t+1) -> sh0[sB]  (independent chain: ILP with cells1)
        {
            float hh[4];
            #pragma unroll
            for (int q = 0; q < 4; ++q)
                hh[q] = cell(acc0[0][q], acc0[1][q], acc0[2][q], acc0[3][q], c0[q]);
            #pragma unroll
            for (int qp = 0; qp < 2; ++qp) {
                unsigned pk = cvtpk(hh[2 * qp], hh[2 * qp + 1]);
                short* b = &sh0[sB][wsidx + qp * 16];
                b[0] = (short)pk; b[8] = (short)(pk >> 16);
            }
        }
        __syncthreads();
    }
    // finals: h0(95) in sh0[1] (written phase 94), h1(95) in sh1[1] (phase 95).
    // sh0[0] holds a discarded h0(96); never read by the decoder.

    // ---- decoder + head weights -> registers ----
    v8s dX0[4][2], dH0[4][2], dX1[4][2], dH1[4][2];
    #pragma unroll
    for (int g = 0; g < 4; ++g) {
        const int n = (w + 4 * g) * 16 + lo;
        #pragma unroll
        for (int kk = 0; kk < 2; ++kk) {
            dX0[g][kk] = ldwf(dWih0, 64, n, kk * 32 + hi * 8);
            dH0[g][kk] = ldwf(dWhh0, 64, n, kk * 32 + hi * 8);
            dX1[g][kk] = ldwf(dWih1, 64, n, kk * 32 + hi * 8);
            dH1[g][kk] = ldwf(dWhh1, 64, n, kk * 32 + hi * 8);
        }
        bz0[g] = db0[g * 64 + w * 16 + lo];
        bz1[g] = db1[g * 64 + w * 16 + lo];
    }
    v8s w1f[2], w2f[2];
    #pragma unroll
    for (int kk = 0; kk < 2; ++kk) {
        w1f[kk] = ldwf(rW1, 64, w * 16 + lo, kk * 32 + hi * 8);
        w2f[kk] = ldwf(rW2, 64, lo, kk * 32 + hi * 8);
    }
    const float hb1 = rb1[w * 16 + lo];
    const float hb2 = rb2[lo];
    float lb[4];
    #pragma unroll
    for (int q = 0; q < 4; ++q) {
        lb[q] = bias[(size_t)(wg * 16 + hi * 4 + q) * 16 + lo];
        c0[q] = 0.f;
        c1[q] = 0.f;
    }

    // ---- dec prologue: acc0 = full l0(0) preactivation from encoder finals
    {
        v8s ah[2], bh[2];
        #pragma unroll
        for (int kk = 0; kk < 2; ++kk) {
            ah[kk] = *(const v8s*)&sh1[1][kk * 512 + lane * 8];   // h_t = h1(95)
            bh[kk] = *(const v8s*)&sh0[1][kk * 512 + lane * 8];   // dh0 = h0(95)
        }
        #pragma unroll
        for (int g = 0; g < 4; ++g)
            acc0[g] = (v4f){bz0[g], bz0[g], bz0[g], bz0[g]};
        #pragma unroll
        for (int kk = 0; kk < 2; ++kk)
            #pragma unroll
            for (int g = 0; g < 4; ++g) {
                acc0[g] = mfma(ah[kk], dX0[g][kk], acc0[g]);
                acc0[g] = mfma(bh[kk], dH0[g][kk], acc0[g]);
            }
    }

    // ============ decoder: A bar1 [GEMM2 | l1] bar2 C(GEMM1 + l0(s+1)) ========
    // A(s): cells0(acc0 from C(s-1)) -> write h0 -> sh0[pw]; hoisted 8 MFMA
    //       Whh1*h1(s-1) into acc1 (sh1[pr] synced since bar2(s-1)).
    // C(s): GEMM1 + sy1 write; pipelined full l0(s+1) (16 MFMA, sh0/sh1[pw]
    //       synced by bar2). sy1: written C(s), read GEMM2 post-bar1(s+1),
    //       overwritten C(s+1) — all barrier-separated.
    #pragma unroll 2
    for (int s = 0; s < 24; ++s) {
        const int pw = s & 1, pr = pw ^ 1;
        // ---- A(s)
        v4f acc1[4];
        {
            v8s bh[2];
            #pragma unroll
            for (int kk = 0; kk < 2; ++kk)
                bh[kk] = *(const v8s*)&sh1[pr][kk * 512 + lane * 8];   // h1(s-1)
            #pragma unroll
            for (int g = 0; g < 4; ++g)
                acc1[g] = (v4f){bz1[g], bz1[g], bz1[g], bz1[g]};
            #pragma unroll
            for (int kk = 0; kk < 2; ++kk)
                #pragma unroll
                for (int g = 0; g < 4; ++g)
                    acc1[g] = mfma(bh[kk], dH1[g][kk], acc1[g]);
        }
        {
            float hh[4];
            #pragma unroll
            for (int q = 0; q < 4; ++q)
                hh[q] = cell(acc0[0][q], acc0[1][q], acc0[2][q], acc0[3][q], c0[q]);
            #pragma unroll
            for (int qp = 0; qp < 2; ++qp) {
                unsigned pk = cvtpk(hh[2 * qp], hh[2 * qp + 1]);
                short* b = &sh0[pw][wsidx + qp * 16];
                b[0] = (short)pk; b[8] = (short)(pk >> 16);
            }
        }
        __syncthreads();                      // bar1: h0(s) ready; sy1(s-1) readable
        // ---- head GEMM2 for step s-1 (wave 0 only), overlaps l1 of other waves
        if (w == 0 && s > 0) {
            v4f a2 = (v4f){hb2, hb2, hb2, hb2};
            #pragma unroll
            for (int kk = 0; kk < 2; ++kk) {
                const v8s a = *(const v8s*)&sy1[kk * 512 + lane * 8];
                a2 = mfma(a, w2f[kk], a2);
            }
            #pragma unroll
            for (int q = 0; q < 4; ++q) {
                size_t row = (size_t)(wg * 16 + hi * 4 + q);
                out[row * 384 + (s - 1) * 16 + lo] = a2[q] + lb[q];
            }
        }
        // ---- l1(s): remaining 8 MFMA + cells1 + write h1
        {
            v8s ah[2];
            #pragma unroll
            for (int kk = 0; kk < 2; ++kk)
                ah[kk] = *(const v8s*)&sh0[pw][kk * 512 + lane * 8];   // h0(s)
            #pragma unroll
            for (int kk = 0; kk < 2; ++kk)
                #pragma unroll
                for (int g = 0; g < 4; ++g)
                    acc1[g] = mfma(ah[kk], dX1[g][kk], acc1[g]);
            float hh[4];
            #pragma unroll
            for (int q = 0; q < 4; ++q)
                hh[q] = cell(acc1[0][q], acc1[1][q], acc1[2][q], acc1[3][q], c1[q]);
            #pragma unroll
            for (int qp = 0; qp < 2; ++qp) {
                unsigned pk = cvtpk(hh[2 * qp], hh[2 * qp + 1]);
                short* b = &sh1[pw][wsidx + qp * 16];
                b[0] = (short)pk; b[8] = (short)(pk >> 16);
            }
        }
        __syncthreads();                      // bar2: h1(s) ready
        // ---- C(s): GEMM1 + sy1 write + pipelined l0(s+1)
        {
            v8s h1f[2], h0f[2];
            #pragma unroll
            for (int kk = 0; kk < 2; ++kk) {
                h1f[kk] = *(const v8s*)&sh1[pw][kk * 512 + lane * 8];   // h1(s)
                h0f[kk] = *(const v8s*)&sh0[pw][kk * 512 + lane * 8];   // h0(s)
            }
            v4f ay = (v4f){hb1, hb1, hb1, hb1};
            #pragma unroll
            for (int kk = 0; kk < 2; ++kk) ay = mfma(h1f[kk], w1f[kk], ay);
            #pragma unroll
            for (int qp = 0; qp < 2; ++qp) {
                unsigned pk = cvtpk(fmaxf(ay[2 * qp], 0.f), fmaxf(ay[2 * qp + 1], 0.f));
                short* b = &sy1[wsidx + qp * 16];
                b[0] = (short)pk; b[8] = (short)(pk >> 16);
            }
            // l0(s+1): 16 MFMA (s=23's result is discarded — negligible waste)
            #pragma unroll
            for (int g = 0; g < 4; ++g)
                acc0[g] = (v4f){bz0[g], bz0[g], bz0[g], bz0[g]};
            #pragma unroll
            for (int kk = 0; kk < 2; ++kk)
                #pragma unroll
                for (int g = 0; g < 4; ++g) {
                    acc0[g] = mfma(h1f[kk], dX0[g][kk], acc0[g]);
                    acc0[g] = mfma(h0f[kk], dH0[g][kk], acc0[g]);
                }
        }
    }
    // ---- drain: head GEMM2 for s=23 ----
    __syncthreads();
    if (w == 0) {
        v4f a2 = (v4f){hb2, hb2, hb2, hb2};
        #pragma unroll
        for (int kk = 0; kk < 2; ++kk) {
            const v8s a = *(const v8s*)&sy1[kk * 512 + lane * 8];
            a2 = mfma(a, w2f[kk], a2);
        }
        #pragma unroll
        for (int q = 0; q < 4; ++q) {
            size_t row = (size_t)(wg * 16 + hi * 4 + q);
            out[row * 384 + 23 * 16 + lo] = a2[q] + lb[q];
        }
    }
}

extern "C" void kernel_launch(void* const* d_in, const int* in_sizes, int n_in,
                              void* d_out, int out_size, void* d_ws, size_t ws_size,
                              hipStream_t stream) {
    seq2seq<<<dim3(1024), dim3(256), 0, stream>>>(
        (const float*)d_in[0],   // X
        (const float*)d_in[1],   // bias   (d_in[2] = X_mask, unused by reference)
        (const float*)d_in[3],  (const float*)d_in[4],  (const float*)d_in[5],
        (const float*)d_in[6],  (const float*)d_in[7],  (const float*)d_in[8],
        (const float*)d_in[9],  (const float*)d_in[10], (const float*)d_in[11],
        (const float*)d_in[12], (const float*)d_in[13], (const float*)d_in[14],
        (const float*)d_in[15], (const float*)d_in[16],
        (const float*)d_in[17], (const float*)d_in[18],
        (float*)d_out);
}